// Round 1
// baseline (632.601 us; speedup 1.0000x reference)
//
#include <hip/hip_runtime.h>

// NLQR: NB=1024, T=128, NS=12, NC=4, N=16.
// Fused backward Riccati scan + forward rollout.
// Decomposition: 16 lanes per batch (lane j = column j of the 16x16 block),
// 4 batches per 64-thread workgroup (one wave), grid = 256.
//
// Backward per step (verified algebra vs reference):
//   F = [A|B] (12x16);  Qt = Q + F^T V F;  qt = p + F^T v
//   kt = -Quu^{-1} qu;  K[:,j] = -Quu^{-1} Qux[:,j]
//   Vn = Qxx + Qxu K        (Schur form of the reference's 4-term expression)
//   vn = qx + Qxu kt
//   u_t = cu_t + kt  -> written straight to d_out (K never needed downstream)
// Forward per step: x' = A x + B u; cost += 0.5*xu^T Q xu + xu.p

#define NBQ 1024
#define TT  128

__device__ __forceinline__ float dot12(const float* sp, const float* f) {
  const float4* v4 = (const float4*)sp;
  float4 a = v4[0], b = v4[1], c = v4[2];
  return a.x*f[0]+a.y*f[1]+a.z*f[2]+a.w*f[3]
       + b.x*f[4]+b.y*f[5]+b.z*f[6]+b.w*f[7]
       + c.x*f[8]+c.y*f[9]+c.z*f[10]+c.w*f[11];
}

__global__ __launch_bounds__(64) void lqr_fused(
    const float* __restrict__ Q, const float* __restrict__ p,
    const float* __restrict__ A, const float* __restrict__ Bm,
    const float* __restrict__ cu, const float* __restrict__ xinit,
    float* __restrict__ out)
{
  // LDS carve (dwords). Per-sub strides chosen so the 4 sub-batches of the
  // wave hit disjoint bank groups on b128 broadcast reads:
  //  FsT stride 196 (%32=4), Vs 148 (%32=20), Qxu 52 (%32=20), QuuT 20, vvS 20.
  __shared__ float lds[3808];
  const int tid = threadIdx.x;
  const int sub = tid >> 4;
  const int j   = tid & 15;
  const long b  = (long)blockIdx.x * 4 + sub;

  float* FsT  = lds + sub*196;            // [16][12]: FsT[n][k] = F[k][n]
  float* Vs   = lds + 784  + sub*148;     // [12][12] row-major
  float* Qxu  = lds + 1376 + sub*52;      // [12][4]
  float* QuuT = lds + 1584 + sub*20;      // [4][4] column-major of Quu
  float* quS  = lds + 1664 + sub*4;       // [4]
  float* vvS  = lds + 1680 + sub*20;      // [12]
  float* uL   = lds + 1760 + sub*512;     // [128][4] u stash for forward pass

  float* xs_out = out;
  float* us_out = out + (long)NBQ*TT*12;
  float* c_out  = out + (long)NBQ*TT*12 + (long)NBQ*TT*4;

  if (j < 12) {
    #pragma unroll
    for (int i = 0; i < 12; ++i) Vs[i*12 + j] = 0.f;
    vvS[j] = 0.f;
  }
  __syncthreads();

  // ---------------- backward Riccati scan (t = T-1 .. 0) ----------------
  #pragma unroll 1
  for (int t = TT-1; t >= 0; --t) {
    const long bt = b*TT + t;
    // Q column j == row j (input Q exactly symmetric) -> coalesced dwordx4.
    const float4* q4p = (const float4*)(Q + bt*256 + j*16);
    float4 q0=q4p[0], q1=q4p[1], q2=q4p[2], q3=q4p[3];
    float qrow[16] = {q0.x,q0.y,q0.z,q0.w, q1.x,q1.y,q1.z,q1.w,
                      q2.x,q2.y,q2.z,q2.w, q3.x,q3.y,q3.z,q3.w};
    const float  pj  = p[bt*16 + j];
    const float4 cu4 = *(const float4*)(cu + bt*4);

    // Stage F^T into LDS (transposed so k is the contiguous axis).
    const float* Ab = A + bt*144;
    #pragma unroll
    for (int s = 0; s < 9; ++s) {
      int idx = j + 16*s;            // 0..143, coalesced global read
      int k = idx / 12, n = idx - k*12;
      FsT[n*12 + k] = Ab[idx];
    }
    const float* Bb = Bm + bt*48;
    #pragma unroll
    for (int s = 0; s < 3; ++s) {
      int idx = j + 16*s;            // 0..47
      int k = idx >> 2, c = idx & 3;
      FsT[(12+c)*12 + k] = Bb[idx];
    }
    __syncthreads();

    // F column j in registers.
    float Fc[12];
    { const float4* f4 = (const float4*)(FsT + j*12);
      float4 a=f4[0], bb=f4[1], cc=f4[2];
      Fc[0]=a.x;Fc[1]=a.y;Fc[2]=a.z;Fc[3]=a.w;
      Fc[4]=bb.x;Fc[5]=bb.y;Fc[6]=bb.z;Fc[7]=bb.w;
      Fc[8]=cc.x;Fc[9]=cc.y;Fc[10]=cc.z;Fc[11]=cc.w; }

    // m = (V F)[:,j]  (b128 broadcast reads of V rows)
    float m[12];
    #pragma unroll
    for (int i = 0; i < 12; ++i) m[i] = dot12(Vs + i*12, Fc);
    // qt-vector component j:  qtv = p_j + (F^T v)_j
    float qtv = pj + dot12(vvS, Fc);

    // Qt column j:  qt[i] = Q[i][j] + sum_k F[k][i] m[k]
    float qt[16];
    #pragma unroll
    for (int i = 0; i < 16; ++i) qt[i] = qrow[i] + dot12(FsT + i*12, m);

    __syncthreads();
    if (j >= 12) {                    // publish Qxu, Quu, qu
      const int c = j - 12;
      #pragma unroll
      for (int i = 0; i < 12; ++i) Qxu[i*4 + c] = qt[i];
      *(float4*)(QuuT + c*4) = make_float4(qt[12],qt[13],qt[14],qt[15]);
      quS[c] = qtv;
    }
    __syncthreads();

    // 4x4 inverse (all lanes redundantly; mm is column-major Quu == QuuT flat).
    float mm[16];
    { const float4* qq = (const float4*)QuuT;
      float4 a=qq[0], bb=qq[1], cc=qq[2], dd=qq[3];
      mm[0]=a.x; mm[1]=a.y; mm[2]=a.z; mm[3]=a.w;
      mm[4]=bb.x; mm[5]=bb.y; mm[6]=bb.z; mm[7]=bb.w;
      mm[8]=cc.x; mm[9]=cc.y; mm[10]=cc.z; mm[11]=cc.w;
      mm[12]=dd.x; mm[13]=dd.y; mm[14]=dd.z; mm[15]=dd.w; }
    float inv[16];
    inv[0]  =  mm[5]*mm[10]*mm[15] - mm[5]*mm[11]*mm[14] - mm[9]*mm[6]*mm[15]
             + mm[9]*mm[7]*mm[14] + mm[13]*mm[6]*mm[11] - mm[13]*mm[7]*mm[10];
    inv[4]  = -mm[4]*mm[10]*mm[15] + mm[4]*mm[11]*mm[14] + mm[8]*mm[6]*mm[15]
             - mm[8]*mm[7]*mm[14] - mm[12]*mm[6]*mm[11] + mm[12]*mm[7]*mm[10];
    inv[8]  =  mm[4]*mm[9]*mm[15] - mm[4]*mm[11]*mm[13] - mm[8]*mm[5]*mm[15]
             + mm[8]*mm[7]*mm[13] + mm[12]*mm[5]*mm[11] - mm[12]*mm[7]*mm[9];
    inv[12] = -mm[4]*mm[9]*mm[14] + mm[4]*mm[10]*mm[13] + mm[8]*mm[5]*mm[14]
             - mm[8]*mm[6]*mm[13] - mm[12]*mm[5]*mm[10] + mm[12]*mm[6]*mm[9];
    inv[1]  = -mm[1]*mm[10]*mm[15] + mm[1]*mm[11]*mm[14] + mm[9]*mm[2]*mm[15]
             - mm[9]*mm[3]*mm[14] - mm[13]*mm[2]*mm[11] + mm[13]*mm[3]*mm[10];
    inv[5]  =  mm[0]*mm[10]*mm[15] - mm[0]*mm[11]*mm[14] - mm[8]*mm[2]*mm[15]
             + mm[8]*mm[3]*mm[14] + mm[12]*mm[2]*mm[11] - mm[12]*mm[3]*mm[10];
    inv[9]  = -mm[0]*mm[9]*mm[15] + mm[0]*mm[11]*mm[13] + mm[8]*mm[1]*mm[15]
             - mm[8]*mm[3]*mm[13] - mm[12]*mm[1]*mm[11] + mm[12]*mm[3]*mm[9];
    inv[13] =  mm[0]*mm[9]*mm[14] - mm[0]*mm[10]*mm[13] - mm[8]*mm[1]*mm[14]
             + mm[8]*mm[2]*mm[13] + mm[12]*mm[1]*mm[10] - mm[12]*mm[2]*mm[9];
    inv[2]  =  mm[1]*mm[6]*mm[15] - mm[1]*mm[7]*mm[14] - mm[5]*mm[2]*mm[15]
             + mm[5]*mm[3]*mm[14] + mm[13]*mm[2]*mm[7] - mm[13]*mm[3]*mm[6];
    inv[6]  = -mm[0]*mm[6]*mm[15] + mm[0]*mm[7]*mm[14] + mm[4]*mm[2]*mm[15]
             - mm[4]*mm[3]*mm[14] - mm[12]*mm[2]*mm[7] + mm[12]*mm[3]*mm[6];
    inv[10] =  mm[0]*mm[5]*mm[15] - mm[0]*mm[7]*mm[13] - mm[4]*mm[1]*mm[15]
             + mm[4]*mm[3]*mm[13] + mm[12]*mm[1]*mm[7] - mm[12]*mm[3]*mm[5];
    inv[14] = -mm[0]*mm[5]*mm[14] + mm[0]*mm[6]*mm[13] + mm[4]*mm[1]*mm[14]
             - mm[4]*mm[2]*mm[13] - mm[12]*mm[1]*mm[6] + mm[12]*mm[2]*mm[5];
    inv[3]  = -mm[1]*mm[6]*mm[11] + mm[1]*mm[7]*mm[10] + mm[5]*mm[2]*mm[11]
             - mm[5]*mm[3]*mm[10] - mm[9]*mm[2]*mm[7] + mm[9]*mm[3]*mm[6];
    inv[7]  =  mm[0]*mm[6]*mm[11] - mm[0]*mm[7]*mm[10] - mm[4]*mm[2]*mm[11]
             + mm[4]*mm[3]*mm[10] + mm[8]*mm[2]*mm[7] - mm[8]*mm[3]*mm[6];
    inv[11] = -mm[0]*mm[5]*mm[11] + mm[0]*mm[7]*mm[9] + mm[4]*mm[1]*mm[11]
             - mm[4]*mm[3]*mm[9] - mm[8]*mm[1]*mm[7] + mm[8]*mm[3]*mm[5];
    inv[15] =  mm[0]*mm[5]*mm[10] - mm[0]*mm[6]*mm[9] - mm[4]*mm[1]*mm[10]
             + mm[4]*mm[2]*mm[9] + mm[8]*mm[1]*mm[6] - mm[8]*mm[2]*mm[5];
    float det  = mm[0]*inv[0] + mm[1]*inv[4] + mm[2]*inv[8] + mm[3]*inv[12];
    float rdet = 1.0f / det;
    #pragma unroll
    for (int i2 = 0; i2 < 16; ++i2) inv[i2] *= rdet;

    float4 quv = *(const float4*)quS;
    // kt[c] = -sum_{c'} Quuinv[c][c'] qu[c'];  Quuinv[c][c'] = inv[c'*4+c]
    float kt0 = -(inv[0]*quv.x + inv[4]*quv.y + inv[8]*quv.z  + inv[12]*quv.w);
    float kt1 = -(inv[1]*quv.x + inv[5]*quv.y + inv[9]*quv.z  + inv[13]*quv.w);
    float kt2 = -(inv[2]*quv.x + inv[6]*quv.y + inv[10]*quv.z + inv[14]*quv.w);
    float kt3 = -(inv[3]*quv.x + inv[7]*quv.y + inv[11]*quv.z + inv[15]*quv.w);

    float u0 = cu4.x + kt0, u1 = cu4.y + kt1, u2 = cu4.z + kt2, u3 = cu4.w + kt3;
    if (j == 0) *(float4*)(uL + t*4) = make_float4(u0,u1,u2,u3);
    if (j < 4) us_out[bt*4 + j] = (j==0)?u0:(j==1)?u1:(j==2)?u2:u3;

    // K column j:  K[c][j] = -sum_{c'} Quuinv[c][c'] Qt[12+c'][j]
    float kc0 = -(inv[0]*qt[12] + inv[4]*qt[13] + inv[8]*qt[14]  + inv[12]*qt[15]);
    float kc1 = -(inv[1]*qt[12] + inv[5]*qt[13] + inv[9]*qt[14]  + inv[13]*qt[15]);
    float kc2 = -(inv[2]*qt[12] + inv[6]*qt[13] + inv[10]*qt[14] + inv[14]*qt[15]);
    float kc3 = -(inv[3]*qt[12] + inv[7]*qt[13] + inv[11]*qt[14] + inv[15]*qt[15]);

    // Vn[:,j] = Qxx[:,j] + Qxu K[:,j];  vn_j = qx_j + (Qxu kt)_j
    float vn[12];
    #pragma unroll
    for (int i = 0; i < 12; ++i) {
      float4 xr = *(const float4*)(Qxu + i*4);
      vn[i] = qt[i] + xr.x*kc0 + xr.y*kc1 + xr.z*kc2 + xr.w*kc3;
    }
    const int jr = (j < 12) ? j : 0;
    float4 xj = *(const float4*)(Qxu + jr*4);
    float vnv = qtv + xj.x*kt0 + xj.y*kt1 + xj.z*kt2 + xj.w*kt3;

    __syncthreads();
    if (j < 12) {
      #pragma unroll
      for (int i = 0; i < 12; ++i) Vs[i*12 + j] = vn[i];
      vvS[j] = vnv;
    }
    __syncthreads();
  }

  // ---------------- forward rollout + cost (t = 0 .. T-1) ----------------
  float xloc = (j < 12) ? xinit[b*12 + j] : 0.f;
  float xu[16];
  #pragma unroll
  for (int mo = 0; mo < 12; ++mo) xu[mo] = __shfl(xloc, mo, 16);
  xu[12]=xu[13]=xu[14]=xu[15]=0.f;
  float cacc = 0.f;

  #pragma unroll 1
  for (int t = 0; t < TT; ++t) {
    const long bt = b*TT + t;
    float4 u4 = *(const float4*)(uL + t*4);
    xu[12]=u4.x; xu[13]=u4.y; xu[14]=u4.z; xu[15]=u4.w;
    float xuloc = xloc;
    if      (j==12) xuloc = u4.x;
    else if (j==13) xuloc = u4.y;
    else if (j==14) xuloc = u4.z;
    else if (j==15) xuloc = u4.w;

    const float4* q4p = (const float4*)(Q + bt*256 + j*16);
    float4 q0=q4p[0], q1=q4p[1], q2=q4p[2], q3=q4p[3];
    float pj = p[bt*16 + j];

    if (j < 12) xs_out[bt*12 + j] = xloc;   // x_t (pre-update)

    float z = q0.x*xu[0]+q0.y*xu[1]+q0.z*xu[2]+q0.w*xu[3]
            + q1.x*xu[4]+q1.y*xu[5]+q1.z*xu[6]+q1.w*xu[7]
            + q2.x*xu[8]+q2.y*xu[9]+q2.z*xu[10]+q2.w*xu[11]
            + q3.x*xu[12]+q3.y*xu[13]+q3.z*xu[14]+q3.w*xu[15];
    cacc += xuloc * (0.5f*z + pj);

    float xn = 0.f;
    if (j < 12) {
      const float4* a4 = (const float4*)(A + bt*144 + j*12);
      float4 a0=a4[0], a1=a4[1], a2=a4[2];
      float4 b4 = *(const float4*)(Bm + bt*48 + j*4);
      xn = a0.x*xu[0]+a0.y*xu[1]+a0.z*xu[2]+a0.w*xu[3]
         + a1.x*xu[4]+a1.y*xu[5]+a1.z*xu[6]+a1.w*xu[7]
         + a2.x*xu[8]+a2.y*xu[9]+a2.z*xu[10]+a2.w*xu[11]
         + b4.x*xu[12]+b4.y*xu[13]+b4.z*xu[14]+b4.w*xu[15];
    }
    xloc = xn;
    #pragma unroll
    for (int mo = 0; mo < 12; ++mo) xu[mo] = __shfl(xn, mo, 16);
  }
  cacc += __shfl_down(cacc, 8, 16);
  cacc += __shfl_down(cacc, 4, 16);
  cacc += __shfl_down(cacc, 2, 16);
  cacc += __shfl_down(cacc, 1, 16);
  if (j == 0) c_out[b] = cacc;
}

extern "C" void kernel_launch(void* const* d_in, const int* in_sizes, int n_in,
                              void* d_out, int out_size, void* d_ws, size_t ws_size,
                              hipStream_t stream) {
  const float* xinit = (const float*)d_in[0];
  // d_in[1] = current_x (unused by reference), d_in[7] = time (unused)
  const float* cu = (const float*)d_in[2];
  const float* Q  = (const float*)d_in[3];
  const float* p  = (const float*)d_in[4];
  const float* A  = (const float*)d_in[5];
  const float* Bm = (const float*)d_in[6];
  float* out = (float*)d_out;

  lqr_fused<<<dim3(NBQ/4), dim3(64), 0, stream>>>(Q, p, A, Bm, cu, xinit, out);
}

// Round 2
// 448.065 us; speedup vs baseline: 1.4119x; 1.4119x over previous
//
#include <hip/hip_runtime.h>

// NLQR: NB=1024, T=128, NS=12, NC=4, N=16.
// Round 2: 64 lanes per batch (1 batch/wave, 1 wave/block, grid=1024 -> 4 waves/CU),
// zero barriers (wave-synchronous LDS), register prefetch of next-t inputs.
//
// Lane roles: (j = l&15, r = l>>4) for the m = V*F step (lane computes m[3r..3r+2][j]);
//             (i4 = l>>2, q4 = l&3) for the Qt tile (lane computes Qt[i4][4q4..4q4+3]).
// Backward algebra (validated in round 1): Qt = Q + F^T V F; qt = p + F^T v;
//   kt = -Quu^{-1} qu; K = -Quu^{-1} Qux; Vn = Qxx + Qxu K; vn = qx + Qxu kt;
//   u_t = cu_t + kt (K never materialized to global).

#define NBQ 1024
#define TT  128

__device__ __forceinline__ float dotf4(float4 a, float4 b) {
  return a.x*b.x + a.y*b.y + a.z*b.z + a.w*b.w;
}
__device__ __forceinline__ float dpp_qx1(float x) {  // quad_perm [1,0,3,2]
  return __int_as_float(__builtin_amdgcn_mov_dpp(__float_as_int(x), 0xB1, 0xF, 0xF, true));
}
__device__ __forceinline__ float dpp_qx2(float x) {  // quad_perm [2,3,0,1]
  return __int_as_float(__builtin_amdgcn_mov_dpp(__float_as_int(x), 0x4E, 0xF, 0xF, true));
}

__global__ __launch_bounds__(64) void lqr_fused(
    const float* __restrict__ Q, const float* __restrict__ p,
    const float* __restrict__ A, const float* __restrict__ Bm,
    const float* __restrict__ cu, const float* __restrict__ xinit,
    float* __restrict__ out)
{
  // LDS carve (dwords), all sub-arrays 16B-aligned. ~4.7 KB/block.
  __shared__ __align__(16) float lds[1184];
  float* FT  = lds;        // [16][12]  FT[n][k] = F[k][n]
  float* Vs  = lds + 192;  // [12][12]  V row-major
  float* msh = lds + 336;  // [12][16]  m = V*F
  float* UxS = lds + 528;  // [4][16]   Qt rows 12..15 (Qux | Quu)
  float* XuS = lds + 592;  // [12][4]   Qxu
  float* quS = lds + 640;  // [4]
  float* vvS = lds + 644;  // [12]
  float* xS  = lds + 656;  // [16]      forward x broadcast
  float* uL  = lds + 672;  // [128][4]  u stash for forward

  const int l  = threadIdx.x;
  const int j  = l & 15;
  const int r  = l >> 4;
  const int i4 = l >> 2;
  const int q4 = l & 3;
  const int c0 = q4 << 2;
  const long b = blockIdx.x;

  float* xs_out = out;
  float* us_out = out + (long)NBQ*TT*12;
  float* c_out  = out + (long)NBQ*TT*12 + (long)NBQ*TT*4;

  // zero-init V, v (harness poisons LDS-adjacent state; LDS itself is ours)
  if (i4 < 12 && q4 < 3) *(float4*)(Vs + i4*12 + c0) = make_float4(0.f,0.f,0.f,0.f);
  if (l < 12) vvS[l] = 0.f;

  // Static staging indices. A-part (lanes 0..35): element e covers flat=4l+e,
  // k=flat/12 (magic mul, exact for flat<144), n=flat%12 -> FT[n*12+k].
  const int aoff = 4*min(l,35);
  const int boff = 4*min(max(l-36,0),11);
  int fta[4];
  #pragma unroll
  for (int e=0;e<4;++e){ int flat=4*l+e; int k=(flat*171)>>11; int n=flat-12*k; fta[e]=n*12+k; }

  long bt = b*TT + (TT-1);
  float4 qv  = *(const float4*)(Q  + bt*256 + 4*l);
  float4 av  = *(const float4*)(A  + bt*144 + aoff);
  float4 bv  = *(const float4*)(Bm + bt*48  + boff);
  float  pv  = p[bt*16 + j];
  float  cuv = cu[bt*4 + q4];

  // ---------------- backward Riccati scan ----------------
  #pragma unroll 1
  for (int t = TT-1; t >= 0; --t) {
    const long btn = bt - (t > 0 ? 1 : 0);
    // prefetch t-1 (independent of the V recursion; lands during this body)
    float4 qn  = *(const float4*)(Q  + btn*256 + 4*l);
    float4 an  = *(const float4*)(A  + btn*144 + aoff);
    float4 bn  = *(const float4*)(Bm + btn*48  + boff);
    float  pn  = p[btn*16 + j];
    float  cun = cu[btn*4 + q4];

    // stage F^T (wave-synchronous; no barrier needed: single wave, in-order DS)
    if (l < 36) {
      FT[fta[0]] = av.x; FT[fta[1]] = av.y; FT[fta[2]] = av.z; FT[fta[3]] = av.w;
    } else if (l < 48) {
      const int kk = l - 36;
      FT[12*12+kk] = bv.x; FT[13*12+kk] = bv.y; FT[14*12+kk] = bv.z; FT[15*12+kk] = bv.w;
    }

    // FT row j (F column j) and FT row i4, v
    const float4* fj4 = (const float4*)(FT + j*12);
    float4 f0 = fj4[0], f1 = fj4[1], f2 = fj4[2];
    const float4* gi4 = (const float4*)(FT + i4*12);
    float4 g0 = gi4[0], g1 = gi4[1], g2 = gi4[2];
    const float4* vv4 = (const float4*)vvS;
    float4 w0 = vv4[0], w1 = vv4[1], w2 = vv4[2];
    float qtv = pv + dotf4(w0,f0) + dotf4(w1,f1) + dotf4(w2,f2);

    // m[3r..3r+2][j] = V rows . F col j
    float m0, m1, m2;
    { const float4* vr = (const float4*)(Vs + (3*r+0)*12);
      m0 = dotf4(vr[0],f0) + dotf4(vr[1],f1) + dotf4(vr[2],f2); }
    { const float4* vr = (const float4*)(Vs + (3*r+1)*12);
      m1 = dotf4(vr[0],f0) + dotf4(vr[1],f1) + dotf4(vr[2],f2); }
    { const float4* vr = (const float4*)(Vs + (3*r+2)*12);
      m2 = dotf4(vr[0],f0) + dotf4(vr[1],f1) + dotf4(vr[2],f2); }
    msh[(3*r+0)*16 + j] = m0;
    msh[(3*r+1)*16 + j] = m1;
    msh[(3*r+2)*16 + j] = m2;

    // Qt[i4][c0..c0+3] = Q + sum_k FT[i4][k] * m[k][c0..c0+3]
    float gk[12] = {g0.x,g0.y,g0.z,g0.w, g1.x,g1.y,g1.z,g1.w, g2.x,g2.y,g2.z,g2.w};
    float4 qt4 = qv;
    #pragma unroll
    for (int k2 = 0; k2 < 12; ++k2) {
      float4 mk = *(const float4*)(msh + k2*16 + c0);
      qt4.x += gk[k2]*mk.x; qt4.y += gk[k2]*mk.y;
      qt4.z += gk[k2]*mk.z; qt4.w += gk[k2]*mk.w;
    }

    // publish Qux|Quu rows, Qxu rows, qu
    if (l >= 48)            *(float4*)(UxS + (i4-12)*16 + c0) = qt4;
    if (q4 == 3 && i4 < 12) *(float4*)(XuS + i4*4) = qt4;
    if (l >= 12 && l < 16)  quS[l-12] = qtv;

    // 4x4 Quu inverse, redundantly in every lane (Quu symmetric)
    float mm[16];
    #pragma unroll
    for (int c = 0; c < 4; ++c) {
      float4 qq = *(const float4*)(UxS + c*16 + 12);
      mm[c*4+0]=qq.x; mm[c*4+1]=qq.y; mm[c*4+2]=qq.z; mm[c*4+3]=qq.w;
    }
    float inv[16];
    inv[0]  =  mm[5]*mm[10]*mm[15] - mm[5]*mm[11]*mm[14] - mm[9]*mm[6]*mm[15]
             + mm[9]*mm[7]*mm[14] + mm[13]*mm[6]*mm[11] - mm[13]*mm[7]*mm[10];
    inv[4]  = -mm[4]*mm[10]*mm[15] + mm[4]*mm[11]*mm[14] + mm[8]*mm[6]*mm[15]
             - mm[8]*mm[7]*mm[14] - mm[12]*mm[6]*mm[11] + mm[12]*mm[7]*mm[10];
    inv[8]  =  mm[4]*mm[9]*mm[15] - mm[4]*mm[11]*mm[13] - mm[8]*mm[5]*mm[15]
             + mm[8]*mm[7]*mm[13] + mm[12]*mm[5]*mm[11] - mm[12]*mm[7]*mm[9];
    inv[12] = -mm[4]*mm[9]*mm[14] + mm[4]*mm[10]*mm[13] + mm[8]*mm[5]*mm[14]
             - mm[8]*mm[6]*mm[13] - mm[12]*mm[5]*mm[10] + mm[12]*mm[6]*mm[9];
    inv[1]  = -mm[1]*mm[10]*mm[15] + mm[1]*mm[11]*mm[14] + mm[9]*mm[2]*mm[15]
             - mm[9]*mm[3]*mm[14] - mm[13]*mm[2]*mm[11] + mm[13]*mm[3]*mm[10];
    inv[5]  =  mm[0]*mm[10]*mm[15] - mm[0]*mm[11]*mm[14] - mm[8]*mm[2]*mm[15]
             + mm[8]*mm[3]*mm[14] + mm[12]*mm[2]*mm[11] - mm[12]*mm[3]*mm[10];
    inv[9]  = -mm[0]*mm[9]*mm[15] + mm[0]*mm[11]*mm[13] + mm[8]*mm[1]*mm[15]
             - mm[8]*mm[3]*mm[13] - mm[12]*mm[1]*mm[11] + mm[12]*mm[3]*mm[9];
    inv[13] =  mm[0]*mm[9]*mm[14] - mm[0]*mm[10]*mm[13] - mm[8]*mm[1]*mm[14]
             + mm[8]*mm[2]*mm[13] + mm[12]*mm[1]*mm[10] - mm[12]*mm[2]*mm[9];
    inv[2]  =  mm[1]*mm[6]*mm[15] - mm[1]*mm[7]*mm[14] - mm[5]*mm[2]*mm[15]
             + mm[5]*mm[3]*mm[14] + mm[13]*mm[2]*mm[7] - mm[13]*mm[3]*mm[6];
    inv[6]  = -mm[0]*mm[6]*mm[15] + mm[0]*mm[7]*mm[14] + mm[4]*mm[2]*mm[15]
             - mm[4]*mm[3]*mm[14] - mm[12]*mm[2]*mm[7] + mm[12]*mm[3]*mm[6];
    inv[10] =  mm[0]*mm[5]*mm[15] - mm[0]*mm[7]*mm[13] - mm[4]*mm[1]*mm[15]
             + mm[4]*mm[3]*mm[13] + mm[12]*mm[1]*mm[7] - mm[12]*mm[3]*mm[5];
    inv[14] = -mm[0]*mm[5]*mm[14] + mm[0]*mm[6]*mm[13] + mm[4]*mm[1]*mm[14]
             - mm[4]*mm[2]*mm[13] - mm[12]*mm[1]*mm[6] + mm[12]*mm[2]*mm[5];
    inv[3]  = -mm[1]*mm[6]*mm[11] + mm[1]*mm[7]*mm[10] + mm[5]*mm[2]*mm[11]
             - mm[5]*mm[3]*mm[10] - mm[9]*mm[2]*mm[7] + mm[9]*mm[3]*mm[6];
    inv[7]  =  mm[0]*mm[6]*mm[11] - mm[0]*mm[7]*mm[10] - mm[4]*mm[2]*mm[11]
             + mm[4]*mm[3]*mm[10] + mm[8]*mm[2]*mm[7] - mm[8]*mm[3]*mm[6];
    inv[11] = -mm[0]*mm[5]*mm[11] + mm[0]*mm[7]*mm[9] + mm[4]*mm[1]*mm[11]
             - mm[4]*mm[3]*mm[9] - mm[8]*mm[1]*mm[7] + mm[8]*mm[3]*mm[5];
    inv[15] =  mm[0]*mm[5]*mm[10] - mm[0]*mm[6]*mm[9] - mm[4]*mm[1]*mm[10]
             + mm[4]*mm[2]*mm[9] + mm[8]*mm[1]*mm[6] - mm[8]*mm[2]*mm[5];
    float det  = mm[0]*inv[0] + mm[1]*inv[4] + mm[2]*inv[8] + mm[3]*inv[12];
    float rdet = 1.0f / det;
    #pragma unroll
    for (int z = 0; z < 16; ++z) inv[z] *= rdet;

    float4 quv = *(const float4*)quS;
    float kt0 = -(inv[0] *quv.x + inv[1] *quv.y + inv[2] *quv.z + inv[3] *quv.w);
    float kt1 = -(inv[4] *quv.x + inv[5] *quv.y + inv[6] *quv.z + inv[7] *quv.w);
    float kt2 = -(inv[8] *quv.x + inv[9] *quv.y + inv[10]*quv.z + inv[11]*quv.w);
    float kt3 = -(inv[12]*quv.x + inv[13]*quv.y + inv[14]*quv.z + inv[15]*quv.w);

    // K[c][c0..c0+3] = -Quu^{-1} Qux (4 b128 reads of UxS col-block)
    float4 ux0 = *(const float4*)(UxS + 0*16 + c0);
    float4 ux1 = *(const float4*)(UxS + 1*16 + c0);
    float4 ux2 = *(const float4*)(UxS + 2*16 + c0);
    float4 ux3 = *(const float4*)(UxS + 3*16 + c0);
    float4 kc[4];
    #pragma unroll
    for (int c = 0; c < 4; ++c) {
      kc[c].x = -(inv[c*4+0]*ux0.x + inv[c*4+1]*ux1.x + inv[c*4+2]*ux2.x + inv[c*4+3]*ux3.x);
      kc[c].y = -(inv[c*4+0]*ux0.y + inv[c*4+1]*ux1.y + inv[c*4+2]*ux2.y + inv[c*4+3]*ux3.y);
      kc[c].z = -(inv[c*4+0]*ux0.z + inv[c*4+1]*ux1.z + inv[c*4+2]*ux2.z + inv[c*4+3]*ux3.z);
      kc[c].w = -(inv[c*4+0]*ux0.w + inv[c*4+1]*ux1.w + inv[c*4+2]*ux2.w + inv[c*4+3]*ux3.w);
    }

    // Vn[i4][c0..c0+3] = Qt + Qxu row . K cols
    if (i4 < 12) {
      float4 xr = *(const float4*)(XuS + i4*4);
      float4 vn4;
      vn4.x = qt4.x + xr.x*kc[0].x + xr.y*kc[1].x + xr.z*kc[2].x + xr.w*kc[3].x;
      vn4.y = qt4.y + xr.x*kc[0].y + xr.y*kc[1].y + xr.z*kc[2].y + xr.w*kc[3].y;
      vn4.z = qt4.z + xr.x*kc[0].z + xr.y*kc[1].z + xr.z*kc[2].z + xr.w*kc[3].z;
      vn4.w = qt4.w + xr.x*kc[0].w + xr.y*kc[1].w + xr.z*kc[2].w + xr.w*kc[3].w;
      if (q4 < 3) *(float4*)(Vs + i4*12 + c0) = vn4;
    }
    if (l < 12) {  // vn vector (lane l has qtv for column j=l)
      float4 xj = *(const float4*)(XuS + l*4);
      vvS[l] = qtv + xj.x*kt0 + xj.y*kt1 + xj.z*kt2 + xj.w*kt3;
    }

    // u_t = cu_t + kt
    float uv = cuv + ((q4==0)?kt0:(q4==1)?kt1:(q4==2)?kt2:kt3);
    if (l < 4) { us_out[bt*4 + l] = uv; uL[t*4 + l] = uv; }

    qv = qn; av = an; bv = bn; pv = pn; cuv = cun; bt = btn;
  }

  // ---------------- forward rollout + cost ----------------
  const int i4c = min(i4, 11);
  float s = xinit[b*12 + i4c];           // row value (valid for i4<12)
  if (q4 == 0 && i4 < 12) xS[i4] = s;

  bt = b*TT;
  float4 qf = *(const float4*)(Q + bt*256 + 4*l);
  float4 ff = (q4 < 3) ? *(const float4*)(A  + bt*144 + i4c*12 + c0)
                       : *(const float4*)(Bm + bt*48  + i4c*4);
  float  pf = p[bt*16 + i4];
  float cacc = 0.f;

  #pragma unroll 1
  for (int t = 0; t < TT; ++t) {
    const long btn2 = bt + (t < TT-1 ? 1 : 0);
    float4 qfn = *(const float4*)(Q + btn2*256 + 4*l);
    float4 ffn = (q4 < 3) ? *(const float4*)(A  + btn2*144 + i4c*12 + c0)
                          : *(const float4*)(Bm + btn2*48  + i4c*4);
    float  pfn = p[btn2*16 + i4];

    float4 u4 = *(const float4*)(uL + t*4);     // broadcast
    float4 xuq = (q4 < 3) ? *(const float4*)(xS + c0) : u4;
    float xui = (i4 < 12) ? s
              : (i4 == 12) ? u4.x : (i4 == 13) ? u4.y : (i4 == 14) ? u4.z : u4.w;

    if (q4 == 0 && i4 < 12) xs_out[bt*12 + i4] = s;   // x_t (pre-update)

    // cost: 0.5 xu^T Q xu as per-lane partials, + xu.p on q4==0 lanes
    float zp = dotf4(qf, xuq);
    cacc += 0.5f * xui * zp;
    if (q4 == 0) cacc += xui * pf;

    // x' rows: quad partial + DPP quad reduction (pure VALU)
    float zx = dotf4(ff, xuq);
    zx += dpp_qx1(zx);
    zx += dpp_qx2(zx);
    s = zx;
    if (q4 == 0 && i4 < 12) xS[i4] = s;

    qf = qfn; ff = ffn; pf = pfn; bt = btn2;
  }

  // final 64-lane cost reduction
  cacc += __shfl_xor(cacc, 32, 64);
  cacc += __shfl_xor(cacc, 16, 64);
  cacc += __shfl_xor(cacc, 8, 64);
  cacc += __shfl_xor(cacc, 4, 64);
  cacc += dpp_qx2(cacc);
  cacc += dpp_qx1(cacc);
  if (l == 0) c_out[b] = cacc;
}

extern "C" void kernel_launch(void* const* d_in, const int* in_sizes, int n_in,
                              void* d_out, int out_size, void* d_ws, size_t ws_size,
                              hipStream_t stream) {
  const float* xinit = (const float*)d_in[0];
  // d_in[1] = current_x (unused by reference), d_in[7] = time (unused)
  const float* cu = (const float*)d_in[2];
  const float* Q  = (const float*)d_in[3];
  const float* p  = (const float*)d_in[4];
  const float* A  = (const float*)d_in[5];
  const float* Bm = (const float*)d_in[6];
  float* out = (float*)d_out;

  lqr_fused<<<dim3(NBQ), dim3(64), 0, stream>>>(Q, p, A, Bm, cu, xinit, out);
}